// Round 9
// baseline (1660.208 us; speedup 1.0000x reference)
//
#include <hip/hip_runtime.h>
#include <hip/hip_bf16.h>

typedef __bf16 bf16x8 __attribute__((ext_vector_type(8)));
typedef float  f32x4  __attribute__((ext_vector_type(4)));

#define MFMA16(a,b,c) __builtin_amdgcn_mfma_f32_16x16x32_bf16((a),(b),(c),0,0,0)

__device__ __forceinline__ bf16x8 cvt8(f32x4 a, f32x4 b){
  bf16x8 r;
  r[0]=(__bf16)a[0]; r[1]=(__bf16)a[1]; r[2]=(__bf16)a[2]; r[3]=(__bf16)a[3];
  r[4]=(__bf16)b[0]; r[5]=(__bf16)b[1]; r[6]=(__bf16)b[2]; r[7]=(__bf16)b[3];
  return r;
}
__device__ __forceinline__ bf16x8 ld8(const float* p){
  return cvt8(*(const f32x4*)p, *(const f32x4*)(p+4));
}
__device__ __forceinline__ float sigm(float x){
  return __builtin_amdgcn_rcpf(1.f + __expf(-x));
}
__device__ __forceinline__ float tanhx(float x){
  return 1.f - 2.f*__builtin_amdgcn_rcpf(1.f + __expf(2.f*x));
}
__device__ __forceinline__ f32x4 sp(float v){ return (f32x4){v,v,v,v}; }

// Layer-split anti-phase co-issue (R7) x 2 independent blocks/CU (R3):
// grid 512 x 512 threads, 4 batch rows/block; waves 0-3 = layer0, 4-7 = layer1.
// Per wave: 64 gate cols (4 tiles, 64 weight regs), EW 1 cell/lane.
extern "C" __global__ void __launch_bounds__(512, 4)
seq2seq_kernel(const float* __restrict__ X,
               const float* __restrict__ Wemb, const float* __restrict__ bemb,
               const float* __restrict__ eWih, const float* __restrict__ eWhh,
               const float* __restrict__ ebih, const float* __restrict__ ebhh,
               const float* __restrict__ dWih, const float* __restrict__ dWhh,
               const float* __restrict__ dbih, const float* __restrict__ dbhh,
               const float* __restrict__ Wreg, const float* __restrict__ breg,
               float* __restrict__ out)
{
  // XA[parity][row][144]: cols 0-63 = x/input, 64-127 = h0 (R3-verified
  // geometry: 0 conflicts). H1s stride 80 bf16 = 40 dw == 8 mod 32;
  // Gm stride 264 dw == 8 mod 32 -> everything <=2-way (free).
  __shared__ __align__(16) __bf16 XA[2][4][144];
  __shared__ __align__(16) __bf16 H1s[4][80];
  __shared__ __align__(16) float  Gm[2][4][264];

  const int tid  = (int)threadIdx.x;
  const int w    = tid >> 6;         // 0..7
  const bool g0  = (w < 4);          // layer-0 group
  const int grp  = w >> 2;
  const int wt   = w & 3;            // wave-in-group; EW row = wt
  const int lane = tid & 63;
  const int col  = lane & 15;
  const int quad = lane >> 4;
  const int row4 = col & 3;          // A real row (M=16 mirrors 4 rows)
  const int b0   = (int)blockIdx.x * 4;
  const int brow = b0 + row4;

  for (int i = tid; i < 2*4*144; i += 512) (&XA[0][0][0])[i] = (__bf16)0.f;
  for (int i = tid; i < 4*80;    i += 512) (&H1s[0][0])[i]   = (__bf16)0.f;

  // ---- persistent weights: layer = grp, cols [64*wt, 64*wt+63] (4 tiles) ----
  bf16x8 wf[16];
  float  gb[4];
#pragma unroll
  for (int j=0; j<4; ++j){
    const int n = 64*wt + 16*j + col;
    gb[j] = ebih[grp*256+n] + ebhh[grp*256+n];
#pragma unroll
    for (int ks=0; ks<4; ++ks){
      const float* srcw = (ks < 2) ? eWih : eWhh;
      wf[j*4+ks] = ld8(srcw + ((size_t)(grp*256+n))*64 + (ks&1)*32 + quad*8);
    }
  }

  // emb fragments + X prefetch: grp0 only (= all waves that run GEMM0)
  const int ue = wt*16 + col;
  bf16x8 wembf;
  float eb = 0.f;
  const float* xb = X + (size_t)brow*512*32 + quad*8;
  f32x4 pa0, pb0, pa1, pb1;
  if (g0){
    wembf = ld8(Wemb + ue*32 + quad*8);
    eb = bemb[ue];
    pa1 = *(const f32x4*)(xb+32); pb1 = *(const f32x4*)(xb+36);   // x(1)
    pa0 = *(const f32x4*)(xb+64); pb0 = *(const f32x4*)(xb+68);   // x(2)
  }

  float cC = 0.f;   // grp0: c0(row wt, unit lane); grp1: c1(row wt, unit lane)

  // grp0: gates of L0(I+1) -> Gm[0]; emb(I+2) -> XA[I&1].x
  auto GEMM0 = [&](const int I){
    const int Px = (I+1)&1, Pr = I&1;
    bf16x8 ax0 = *(const bf16x8*)&XA[Px][row4][ 0 + quad*8];
    bf16x8 ax1 = *(const bf16x8*)&XA[Px][row4][32 + quad*8];
    bf16x8 ah0 = *(const bf16x8*)&XA[Pr][row4][64 + quad*8];
    bf16x8 ah1 = *(const bf16x8*)&XA[Pr][row4][96 + quad*8];
    f32x4 A0=sp(gb[0]), A1=sp(gb[1]), A2=sp(gb[2]), A3=sp(gb[3]);
    A0=MFMA16(ax0,wf[0],A0);  A1=MFMA16(ax0,wf[4],A1);
    A2=MFMA16(ax0,wf[8],A2);  A3=MFMA16(ax0,wf[12],A3);
    A0=MFMA16(ax1,wf[1],A0);  A1=MFMA16(ax1,wf[5],A1);
    A2=MFMA16(ax1,wf[9],A2);  A3=MFMA16(ax1,wf[13],A3);
    A0=MFMA16(ah0,wf[2],A0);  A1=MFMA16(ah0,wf[6],A1);
    A2=MFMA16(ah0,wf[10],A2); A3=MFMA16(ah0,wf[14],A3);
    A0=MFMA16(ah1,wf[3],A0);  A1=MFMA16(ah1,wf[7],A1);
    A2=MFMA16(ah1,wf[11],A2); A3=MFMA16(ah1,wf[15],A3);
    if (I < 510){
      const int s = I&1;
      f32x4 xr0 = s ? pa1 : pa0, xr1 = s ? pb1 : pb0;
      f32x4 ea = MFMA16(cvt8(xr0,xr1), wembf, sp(eb));
      int tn = I+4; if (tn > 511) tn = 511;
      f32x4 na = *(const f32x4*)(xb + (size_t)tn*32);
      f32x4 nb = *(const f32x4*)(xb + (size_t)tn*32 + 4);
      if (s){ pa1=na; pb1=nb; } else { pa0=na; pb0=nb; }
      if (quad == 0){                    // C rows quad*4+r: quad0 = real rows
#pragma unroll
        for (int r=0; r<4; ++r) XA[s][r][ue] = (__bf16)ea[r];
      }
    }
    // every quad holds a full 4-row copy; quad q stores tile q
    f32x4 u0 = (quad&1) ? A1 : A0;
    f32x4 u1 = (quad&1) ? A3 : A2;
    f32x4 t  = (quad&2) ? u1 : u0;
    const int nn = 64*wt + 16*quad + col;
#pragma unroll
    for (int r=0; r<4; ++r) Gm[0][r][nn] = t[r];
  };

  // grp1: gates of L1(I) = [h0(I) | h1(I-1)] -> Gm[1]
  auto GEMM1 = [&](const int I){
    const int Pr = I&1;
    bf16x8 ah0 = *(const bf16x8*)&XA[Pr][row4][64 + quad*8];
    bf16x8 ah1 = *(const bf16x8*)&XA[Pr][row4][96 + quad*8];
    bf16x8 ag0 = *(const bf16x8*)&H1s[row4][quad*8];
    bf16x8 ag1 = *(const bf16x8*)&H1s[row4][32 + quad*8];
    f32x4 A0=sp(gb[0]), A1=sp(gb[1]), A2=sp(gb[2]), A3=sp(gb[3]);
    A0=MFMA16(ah0,wf[0],A0);  A1=MFMA16(ah0,wf[4],A1);
    A2=MFMA16(ah0,wf[8],A2);  A3=MFMA16(ah0,wf[12],A3);
    A0=MFMA16(ah1,wf[1],A0);  A1=MFMA16(ah1,wf[5],A1);
    A2=MFMA16(ah1,wf[9],A2);  A3=MFMA16(ah1,wf[13],A3);
    A0=MFMA16(ag0,wf[2],A0);  A1=MFMA16(ag0,wf[6],A1);
    A2=MFMA16(ag0,wf[10],A2); A3=MFMA16(ag0,wf[14],A3);
    A0=MFMA16(ag1,wf[3],A0);  A1=MFMA16(ag1,wf[7],A1);
    A2=MFMA16(ag1,wf[11],A2); A3=MFMA16(ag1,wf[15],A3);
    f32x4 u0 = (quad&1) ? A1 : A0;
    f32x4 u1 = (quad&1) ? A3 : A2;
    f32x4 t  = (quad&2) ? u1 : u0;
    const int nn = 64*wt + 16*quad + col;
#pragma unroll
    for (int r=0; r<4; ++r) Gm[1][r][nn] = t[r];
  };

  // grp0 EW: 1 cell (row wt, unit lane) -> h0(I+1) at parity (I+1)&1
  auto EW0 = [&](const int I){
    const int Pw = (I+1)&1;
    const float* g = Gm[0][wt];
    float i0=sigm(g[lane]),      f0=sigm(g[64+lane]);
    float gg=tanhx(g[128+lane]), o0=sigm(g[192+lane]);
    cC = f0*cC + i0*gg;
    XA[Pw][wt][64+lane] = (__bf16)(o0*tanhx(cC));
  };

  // grp1 EW -> h1 (single buffer)
  auto EW1 = [&](){
    const float* g = Gm[1][wt];
    float i1=sigm(g[lane]),      f1=sigm(g[64+lane]);
    float gg=tanhx(g[128+lane]), o1=sigm(g[192+lane]);
    cC = f1*cC + i1*gg;
    H1s[wt][lane] = (__bf16)(o1*tanhx(cC));
  };

  __syncthreads();                 // zero-init visible

  // ---- prologue ----
  if (g0){
    f32x4 x0a = *(const f32x4*)xb, x0b = *(const f32x4*)(xb+4);
    f32x4 e0 = MFMA16(cvt8(x0a,x0b), wembf, sp(eb));
    if (quad == 0){
#pragma unroll
      for (int r=0; r<4; ++r) XA[0][r][ue] = (__bf16)e0[r];
    }
  }
  __syncthreads();
  if (g0) GEMM0(-1);               // L0(0) gates + emb(1)
  __syncthreads();
  if (g0) EW0(-1);                 // h0(0) -> parity 0
  __syncthreads();

  // ---- steady encoder: slot I computes L0(I+1) & L1(I); 2 barriers/slot ----
#define SLOT(I)                                              \
  if (g0) GEMM0(I); else { if ((I) > 0) EW1(); }             \
  __syncthreads();                                           \
  if (g0) EW0(I); else GEMM1(I);                             \
  __syncthreads();

  for (int ii=0; ii<255; ++ii){
    SLOT(2*ii)
    SLOT(2*ii+1)
  }
  SLOT(510)
#undef SLOT

  // ---- epilogue: L1(511) ----
  if (!g0) EW1();                  // h1(510)
  __syncthreads();
  if (!g0) GEMM1(511);             // reads h0(511) (parity 1), h1(510)
  __syncthreads();
  if (!g0) EW1();                  // h1(511)
  __syncthreads();

  // ================= decoder =================
  // init: XA[0] = [input=h1(511) | h0(511)]; H1s = h1(511); c = 0
  for (int idx = tid; idx < 4*128; idx += 512){
    int r = idx >> 7, cc = idx & 127;
    XA[0][r][cc] = (cc < 64) ? H1s[r][cc] : XA[1][r][cc];
  }
  // regression head (loaded late)
  bf16x8 wr0 = ld8(Wreg + (col&7)*64 +  0 + quad*8);
  bf16x8 wr1 = ld8(Wreg + (col&7)*64 + 32 + quad*8);
  const float rb = breg[col&7];
  // decoder weights: wave w covers gate cols [32w, 32w+31], BOTH layers
#pragma unroll
  for (int l=0; l<2; ++l)
#pragma unroll
    for (int ti=0; ti<2; ++ti){
      const int n = 32*w + 16*ti + col;
      gb[l*2+ti] = dbih[l*256+n] + dbhh[l*256+n];
#pragma unroll
      for (int ks=0; ks<4; ++ks){
        const float* srcw = (ks < 2) ? dWih : dWhh;
        wf[(l*2+ti)*4+ks] = ld8(srcw + ((size_t)(l*256+n))*64 + (ks&1)*32 + quad*8);
      }
    }
  cC = 0.f;
  __syncthreads();

  auto Ystore = [&](const int t){
    f32x4 ya = sp(rb);
    bf16x8 y0 = *(const bf16x8*)&H1s[row4][quad*8];
    bf16x8 y1 = *(const bf16x8*)&H1s[row4][32 + quad*8];
    ya = MFMA16(y0, wr0, ya);
    ya = MFMA16(y1, wr1, ya);
    if (quad == 0 && col < 8){           // quad0 regs hold real rows 0..3
#pragma unroll
      for (int r=0; r<4; ++r)
        out[((size_t)(b0 + r)*48 + t)*8 + col] = ya[r];
    }
  };

  for (int t=0; t<48; ++t){
    { // P1: GEMM-L0 = [input | h0], all 8 waves (2 tiles)
      bf16x8 ax0 = *(const bf16x8*)&XA[0][row4][ 0 + quad*8];
      bf16x8 ax1 = *(const bf16x8*)&XA[0][row4][32 + quad*8];
      bf16x8 ah0 = *(const bf16x8*)&XA[0][row4][64 + quad*8];
      bf16x8 ah1 = *(const bf16x8*)&XA[0][row4][96 + quad*8];
      f32x4 B0 = sp(gb[0]), B1 = sp(gb[1]);
      B0=MFMA16(ax0,wf[0],B0); B1=MFMA16(ax0,wf[4],B1);
      B0=MFMA16(ax1,wf[1],B0); B1=MFMA16(ax1,wf[5],B1);
      B0=MFMA16(ah0,wf[2],B0); B1=MFMA16(ah0,wf[6],B1);
      B0=MFMA16(ah1,wf[3],B0); B1=MFMA16(ah1,wf[7],B1);
      if (quad < 2){
        f32x4 t0 = (quad&1) ? B1 : B0;
        const int nn = 32*w + ((quad&1)?16:0) + col;
#pragma unroll
        for (int r=0; r<4; ++r) Gm[0][r][nn] = t0[r];
      }
      if (t && w == 0) Ystore(t-1);
    }
    __syncthreads();
    if (w < 4){ // P2: EW-L0 (row w)
      const float* g = Gm[0][w];
      float i0=sigm(g[lane]),      f0=sigm(g[64+lane]);
      float gg=tanhx(g[128+lane]), o0=sigm(g[192+lane]);
      cC = f0*cC + i0*gg;
      XA[0][w][64+lane] = (__bf16)(o0*tanhx(cC));
    }
    __syncthreads();
    { // P3: GEMM-L1 = [h0 | h1], all 8 waves
      bf16x8 ah0 = *(const bf16x8*)&XA[0][row4][64 + quad*8];
      bf16x8 ah1 = *(const bf16x8*)&XA[0][row4][96 + quad*8];
      bf16x8 ag0 = *(const bf16x8*)&H1s[row4][quad*8];
      bf16x8 ag1 = *(const bf16x8*)&H1s[row4][32 + quad*8];
      f32x4 B0 = sp(gb[2]), B1 = sp(gb[3]);
      B0=MFMA16(ah0,wf[8],B0);  B1=MFMA16(ah0,wf[12],B1);
      B0=MFMA16(ah1,wf[9],B0);  B1=MFMA16(ah1,wf[13],B1);
      B0=MFMA16(ag0,wf[10],B0); B1=MFMA16(ag0,wf[14],B1);
      B0=MFMA16(ag1,wf[11],B0); B1=MFMA16(ag1,wf[15],B1);
      if (quad < 2){
        f32x4 t0 = (quad&1) ? B1 : B0;
        const int nn = 32*w + ((quad&1)?16:0) + col;
#pragma unroll
        for (int r=0; r<4; ++r) Gm[1][r][nn] = t0[r];
      }
    }
    __syncthreads();
    if (w >= 4){ // P4: EW-L1 (row w-4) -> h1 + feedback input
      const int rw = w - 4;
      const float* g = Gm[1][rw];
      float i1=sigm(g[lane]),      f1=sigm(g[64+lane]);
      float gg=tanhx(g[128+lane]), o1=sigm(g[192+lane]);
      cC = f1*cC + i1*gg;
      __bf16 hb = (__bf16)(o1*tanhx(cC));
      H1s[rw][lane]   = hb;
      XA[0][rw][lane] = hb;
    }
    __syncthreads();
  }
  if (w == 0) Ystore(47);
}

extern "C" void kernel_launch(void* const* d_in, const int* in_sizes, int n_in,
                              void* d_out, int out_size, void* d_ws, size_t ws_size,
                              hipStream_t stream)
{
  (void)in_sizes; (void)n_in; (void)out_size; (void)d_ws; (void)ws_size;
  const float* X    = (const float*)d_in[0];
  const float* Wemb = (const float*)d_in[2];
  const float* bemb = (const float*)d_in[3];
  const float* eWih = (const float*)d_in[4];
  const float* eWhh = (const float*)d_in[5];
  const float* ebih = (const float*)d_in[6];
  const float* ebhh = (const float*)d_in[7];
  const float* dWih = (const float*)d_in[8];
  const float* dWhh = (const float*)d_in[9];
  const float* dbih = (const float*)d_in[10];
  const float* dbhh = (const float*)d_in[11];
  const float* Wreg = (const float*)d_in[12];
  const float* breg = (const float*)d_in[13];
  float* out = (float*)d_out;

  seq2seq_kernel<<<dim3(512), dim3(512), 0, stream>>>(
      X, Wemb, bemb, eWih, eWhh, ebih, ebhh,
      dWih, dWhh, dbih, dbhh, Wreg, breg, out);
}